// Round 1
// baseline (191.702 us; speedup 1.0000x reference)
//
#include <hip/hip_runtime.h>

#define BB 2
#define NN 4096
#define DD 1024
#define HH 16
#define RR 4
#define MM 8
#define BUCKET 64
#define CC (NN / BUCKET)   // 64 buckets
#define DH (DD / HH)       // 64 head dim
#define PAD 68             // LDS row stride (floats), 16B-aligned, breaks bank conflicts

union F4 { float4 v; float f[4]; };

// ---------------------------------------------------------------------------
// Kernel 1: LSH hash codes.  codes[b,r,h,n] = argmax_m sum_d Q[b,n,h*64+d]*P[r,h,d,m]
// grid = B*H*C blocks (each owns 64 consecutive n), 256 threads.
// ---------------------------------------------------------------------------
__global__ __launch_bounds__(256) void k_hash(const float* __restrict__ q,
                                              const float* __restrict__ proj,
                                              int* __restrict__ codes) {
  int blk = blockIdx.x;
  int nc = blk & (CC - 1);
  int h = (blk >> 6) & (HH - 1);
  int b = blk >> 10;
  __shared__ float Qs[64][PAD];
  __shared__ float Ps[DH][MM];
  __shared__ float Ss[64][9];
  int tid = threadIdx.x;
  const float* qbase = q + ((size_t)(b * NN + nc * 64) * DD + h * DH);
  for (int f = tid; f < 1024; f += 256) {
    int row = f >> 4, c4 = f & 15;
    *(float4*)&Qs[row][c4 * 4] = *(const float4*)(qbase + (size_t)row * DD + c4 * 4);
  }
  int nl = tid >> 3, m = tid & 7;
  for (int r = 0; r < RR; ++r) {
    const float* pbase = proj + (size_t)(r * HH + h) * DH * MM;
    for (int f = tid; f < DH * MM / 4; f += 256)
      ((float4*)Ps)[f] = ((const float4*)pbase)[f];
    __syncthreads();
    float s0 = 0.f, s1 = 0.f;
#pragma unroll
    for (int kk = 0; kk < DH; ++kk) {
      float p = Ps[kk][m];
      s0 += Qs[nl][kk] * p;
      s1 += Qs[nl + 32][kk] * p;
    }
    Ss[nl][m] = s0;
    Ss[nl + 32][m] = s1;
    __syncthreads();
    if (tid < 64) {
      float best = Ss[tid][0];
      int bm = 0;
#pragma unroll
      for (int mm = 1; mm < MM; ++mm) {
        float vv = Ss[tid][mm];
        if (vv > best) { best = vv; bm = mm; }  // first-max tie-break (jnp.argmax)
      }
      codes[(size_t)((b * RR + r) * HH + h) * NN + nc * 64 + tid] = bm;
    }
    __syncthreads();
  }
}

// ---------------------------------------------------------------------------
// Kernel 2: stable counting sort of 4096 codes (values 0..7) per (b,r,h).
// Matches jnp.argsort(stable) ascending. grid = B*R*H, 256 threads.
// NOTE: valence scaling of codes is a monotone map -> sort order unchanged; ignored.
// ---------------------------------------------------------------------------
__global__ __launch_bounds__(256) void k_sort(const int* __restrict__ codes,
                                              int* __restrict__ idxo) {
  int g = blockIdx.x;
  const int* cg = codes + (size_t)g * NN;
  int* ig = idxo + (size_t)g * NN;
  __shared__ int hist[256][MM];
  __shared__ int startk[MM];
  int tid = threadIdx.x;
  int myc[16];
#pragma unroll
  for (int qd = 0; qd < 4; ++qd) {
    int4 t4 = ((const int4*)(cg + tid * 16))[qd];
    myc[qd * 4 + 0] = t4.x; myc[qd * 4 + 1] = t4.y;
    myc[qd * 4 + 2] = t4.z; myc[qd * 4 + 3] = t4.w;
  }
  // packed per-thread histogram (8 codes x 8 bits; max count 16 fits)
  unsigned long long cnt64 = 0ull;
#pragma unroll
  for (int i = 0; i < 16; ++i) cnt64 += 1ull << (myc[i] * 8);
#pragma unroll
  for (int k = 0; k < MM; ++k) hist[tid][k] = (int)((cnt64 >> (k * 8)) & 0xffull);
  __syncthreads();
  if (tid < MM) {  // exclusive scan over threads per code + code totals
    int run = 0;
    for (int t = 0; t < 256; ++t) { int vv = hist[t][tid]; hist[t][tid] = run; run += vv; }
    startk[tid] = run;
  }
  __syncthreads();
  if (tid == 0) {  // exclusive scan over codes
    int base = 0;
#pragma unroll
    for (int k = 0; k < MM; ++k) { int vv = startk[k]; startk[k] = base; base += vv; }
  }
  __syncthreads();
#pragma unroll
  for (int i = 0; i < 16; ++i) {  // stable placement
    int k = myc[i];
    int off = hist[tid][k];
    hist[tid][k] = off + 1;
    ig[startk[k] + off] = tid * 16 + i;
  }
}

__device__ __forceinline__ void fma4x4(float acc[4][4], const F4 av[4], const F4 bv[4]) {
#pragma unroll
  for (int i = 0; i < 4; ++i)
#pragma unroll
    for (int j = 0; j < 4; ++j)
      acc[i][j] += av[i].f[0] * bv[0].f[j] + av[i].f[1] * bv[1].f[j] +
                   av[i].f[2] * bv[2].f[j] + av[i].f[3] * bv[3].f[j];
}

// ---------------------------------------------------------------------------
// Kernel 3: bucketed attention. grid = B*H*C blocks (loop r inside -> register
// accumulation of the r-mean output and r-sum of attention probs), 256 threads
// as 16x16, each computing a 4x4 tile of the 64x64 bucket matrices.
// ---------------------------------------------------------------------------
__global__ __launch_bounds__(256) void k_attn(const float* __restrict__ q,
                                              const float* __restrict__ kmat,
                                              const float* __restrict__ vmat,
                                              const int* __restrict__ idxs,
                                              float* __restrict__ out,
                                              float* __restrict__ attn_part,
                                              float* __restrict__ attn_out,
                                              int atomic_attn) {
  int blk = blockIdx.x;
  int c = blk & (CC - 1);
  int h = (blk >> 6) & (HH - 1);
  int b = blk >> 10;
  __shared__ float Qs[64][PAD];
  __shared__ float KT[64][PAD];  // K transposed: KT[d][e]; reused as P[s][e] after scores
  __shared__ float Vs[64][PAD];  // V row-major: Vs[e][d]
  __shared__ int sidx[64];
  int tid = threadIdx.x;
  int tx = tid & 15, ty = tid >> 4;

  const float* qbase = q + ((size_t)(b * NN + c * 64) * DD + h * DH);
  for (int f = tid; f < 1024; f += 256) {
    int row = f >> 4, c4 = f & 15;
    *(float4*)&Qs[row][c4 * 4] = *(const float4*)(qbase + (size_t)row * DD + c4 * 4);
  }
  float acc_o[4][4], attA[4][4];
#pragma unroll
  for (int i = 0; i < 4; ++i)
#pragma unroll
    for (int j = 0; j < 4; ++j) { acc_o[i][j] = 0.f; attA[i][j] = 0.f; }

  const size_t kvbase = (size_t)b * NN * DD + (size_t)h * DH;
  for (int r = 0; r < RR; ++r) {
    if (tid < 64) sidx[tid] = idxs[(size_t)((b * RR + r) * HH + h) * NN + c * 64 + tid];
    __syncthreads();
    // gather K (transposed) and V rows for this bucket
    for (int f = tid; f < 1024; f += 256) {
      int e = f >> 4, c4 = f & 15;
      int n = sidx[e];
      F4 kv, vv;
      kv.v = *(const float4*)(kmat + kvbase + (size_t)n * DD + c4 * 4);
      vv.v = *(const float4*)(vmat + kvbase + (size_t)n * DD + c4 * 4);
      KT[c4 * 4 + 0][e] = kv.f[0];
      KT[c4 * 4 + 1][e] = kv.f[1];
      KT[c4 * 4 + 2][e] = kv.f[2];
      KT[c4 * 4 + 3][e] = kv.f[3];
      *(float4*)&Vs[e][c4 * 4] = vv.v;
    }
    __syncthreads();
    // scores S[s][e] = (1/8) * sum_k Q[s][k]*K[e][k]
    float acc_s[4][4];
#pragma unroll
    for (int i = 0; i < 4; ++i)
#pragma unroll
      for (int j = 0; j < 4; ++j) acc_s[i][j] = 0.f;
#pragma unroll 4
    for (int kq = 0; kq < DH; kq += 4) {
      F4 av[4], bv[4];
#pragma unroll
      for (int i = 0; i < 4; ++i) av[i].v = *(const float4*)&Qs[ty * 4 + i][kq];
#pragma unroll
      for (int u = 0; u < 4; ++u) bv[u].v = *(const float4*)&KT[kq + u][tx * 4];
      fma4x4(acc_s, av, bv);
    }
    // softmax over e (rows live across the 16 tx-lanes of each wave 16-group)
#pragma unroll
    for (int i = 0; i < 4; ++i) {
#pragma unroll
      for (int j = 0; j < 4; ++j) acc_s[i][j] *= 0.125f;
      float mx = fmaxf(fmaxf(acc_s[i][0], acc_s[i][1]), fmaxf(acc_s[i][2], acc_s[i][3]));
      mx = fmaxf(mx, __shfl_xor(mx, 1));
      mx = fmaxf(mx, __shfl_xor(mx, 2));
      mx = fmaxf(mx, __shfl_xor(mx, 4));
      mx = fmaxf(mx, __shfl_xor(mx, 8));
      float sm = 0.f;
#pragma unroll
      for (int j = 0; j < 4; ++j) { acc_s[i][j] = __expf(acc_s[i][j] - mx); sm += acc_s[i][j]; }
      sm += __shfl_xor(sm, 1);
      sm += __shfl_xor(sm, 2);
      sm += __shfl_xor(sm, 4);
      sm += __shfl_xor(sm, 8);
      float inv = 1.f / sm;
#pragma unroll
      for (int j = 0; j < 4; ++j) { acc_s[i][j] *= inv; attA[i][j] += acc_s[i][j]; }
    }
    __syncthreads();  // everyone done reading KT -> reuse as P
#pragma unroll
    for (int i = 0; i < 4; ++i) {
      F4 pv;
#pragma unroll
      for (int j = 0; j < 4; ++j) pv.f[j] = acc_s[i][j];
      *(float4*)&KT[ty * 4 + i][tx * 4] = pv.v;
    }
    __syncthreads();
    // O[s][d] += sum_e P[s][e]*V[e][d]   (accumulates across r)
#pragma unroll 4
    for (int eq = 0; eq < 64; eq += 4) {
      F4 av[4], bv[4];
#pragma unroll
      for (int i = 0; i < 4; ++i) av[i].v = *(const float4*)&KT[ty * 4 + i][eq];
#pragma unroll
      for (int u = 0; u < 4; ++u) bv[u].v = *(const float4*)&Vs[eq + u][tx * 4];
      fma4x4(acc_o, av, bv);
    }
    __syncthreads();  // before next r overwrites KT/Vs/sidx
  }
  // epilogue: out[b][n][h*64+d] = mean_r O
  const float invR = 1.f / RR;
#pragma unroll
  for (int i = 0; i < 4; ++i) {
    F4 o;
#pragma unroll
    for (int j = 0; j < 4; ++j) o.f[j] = acc_o[i][j] * invR;
    *(float4*)(out + (size_t)(b * NN + c * 64 + ty * 4 + i) * DD + h * DH + tx * 4) = o.v;
  }
  if (atomic_attn) {
    const float sc = 1.f / (RR * HH);
#pragma unroll
    for (int i = 0; i < 4; ++i)
#pragma unroll
      for (int j = 0; j < 4; ++j)
        atomicAdd(attn_out + (((size_t)b * CC + c) * 64 + ty * 4 + i) * 64 + tx * 4 + j,
                  attA[i][j] * sc);
  } else {
#pragma unroll
    for (int i = 0; i < 4; ++i) {
      F4 o;
#pragma unroll
      for (int j = 0; j < 4; ++j) o.f[j] = attA[i][j];
      *(float4*)(attn_part + (((size_t)(b * HH + h) * CC + c) * 64 + ty * 4 + i) * 64 + tx * 4) = o.v;
    }
  }
}

// ---------------------------------------------------------------------------
// Kernel 4: attn_out[b][c][s][e] = (1/(R*H)) * sum_h attn_part[b][h][c][s][e]
// ---------------------------------------------------------------------------
__global__ __launch_bounds__(256) void k_attn_reduce(const float* __restrict__ part,
                                                     float* __restrict__ attn_out) {
  size_t o = (size_t)blockIdx.x * 256 + threadIdx.x;
  int se = (int)(o & 4095);
  size_t bc = o >> 12;
  int c = (int)(bc & (CC - 1));
  int b = (int)(bc >> 6);
  float s = 0.f;
  const float* p = part + ((size_t)b * HH * CC + c) * 4096 + se;
#pragma unroll
  for (int h = 0; h < HH; ++h) s += p[(size_t)h * CC * 4096];
  attn_out[o] = s * (1.f / (RR * HH));
}

extern "C" void kernel_launch(void* const* d_in, const int* in_sizes, int n_in,
                              void* d_out, int out_size, void* d_ws, size_t ws_size,
                              hipStream_t stream) {
  const float* q = (const float*)d_in[0];
  const float* k = (const float*)d_in[1];
  const float* v = (const float*)d_in[2];
  // d_in[3] (valence) and d_in[5] (valence_scale) only scale codes by a positive
  // integer -> argsort order is invariant -> dead inputs.
  const float* proj = (const float*)d_in[4];
  float* out = (float*)d_out;
  float* attn_out = out + (size_t)BB * NN * DD;

  int* codes = (int*)d_ws;
  int* idxs = codes + (size_t)BB * RR * HH * NN;
  float* attn_part = (float*)(idxs + (size_t)BB * RR * HH * NN);
  size_t need = (size_t)BB * RR * HH * NN * 8 + (size_t)BB * HH * CC * 4096 * 4;
  int atomic_attn = (ws_size < need) ? 1 : 0;
  if (atomic_attn)
    hipMemsetAsync(attn_out, 0, (size_t)BB * CC * 4096 * sizeof(float), stream);

  k_hash<<<BB * HH * CC, 256, 0, stream>>>(q, proj, codes);
  k_sort<<<BB * RR * HH, 256, 0, stream>>>(codes, idxs);
  k_attn<<<BB * HH * CC, 256, 0, stream>>>(q, k, v, idxs, out, attn_part, attn_out, atomic_attn);
  if (!atomic_attn)
    k_attn_reduce<<<BB * CC * 4096 / 256, 256, 0, stream>>>(attn_part, attn_out);
}

// Round 2
// 109.706 us; speedup vs baseline: 1.7474x; 1.7474x over previous
//
#include <hip/hip_runtime.h>

#define BB 2
#define NN 4096
#define DD 1024
#define HH 16
#define RR 4
#define MM 8
#define CC 64
#define DH 64
#define PAD 68

typedef __attribute__((ext_vector_type(8))) short bf16x8;
typedef __attribute__((ext_vector_type(4))) float f32x4;
typedef unsigned long long u64;

__device__ __forceinline__ unsigned short f2bf(float x) {
  unsigned u = __float_as_uint(x);
  unsigned r = (u + 0x7fffu + ((u >> 16) & 1u)) >> 16;
  return (unsigned short)r;
}
__device__ __forceinline__ float bf2f(unsigned short s) {
  return __uint_as_float(((unsigned)s) << 16);
}
// swizzled byte address in a [64 rows][128 bytes] LDS tile (conflict-free b128)
__device__ __forceinline__ int swz(int row, int colbyte) {
  return row * 128 + (colbyte ^ ((row & 7) << 4));
}

// ---------------------------------------------------------------------------
// Kernel 1: LSH hash codes (unchanged from round 1 — ~2 µs)
// ---------------------------------------------------------------------------
__global__ __launch_bounds__(256) void k_hash(const float* __restrict__ q,
                                              const float* __restrict__ proj,
                                              int* __restrict__ codes) {
  int blk = blockIdx.x;
  int nc = blk & (CC - 1);
  int h = (blk >> 6) & (HH - 1);
  int b = blk >> 10;
  __shared__ float Qs[64][PAD];
  __shared__ float Ps[DH][MM];
  __shared__ float Ss[64][9];
  int tid = threadIdx.x;
  const float* qbase = q + ((size_t)(b * NN + nc * 64) * DD + h * DH);
  for (int f = tid; f < 1024; f += 256) {
    int row = f >> 4, c4 = f & 15;
    *(float4*)&Qs[row][c4 * 4] = *(const float4*)(qbase + (size_t)row * DD + c4 * 4);
  }
  int nl = tid >> 3, m = tid & 7;
  for (int r = 0; r < RR; ++r) {
    const float* pbase = proj + (size_t)(r * HH + h) * DH * MM;
    for (int f = tid; f < DH * MM / 4; f += 256)
      ((float4*)Ps)[f] = ((const float4*)pbase)[f];
    __syncthreads();
    float s0 = 0.f, s1 = 0.f;
#pragma unroll
    for (int kk = 0; kk < DH; ++kk) {
      float p = Ps[kk][m];
      s0 += Qs[nl][kk] * p;
      s1 += Qs[nl + 32][kk] * p;
    }
    Ss[nl][m] = s0;
    Ss[nl + 32][m] = s1;
    __syncthreads();
    if (tid < 64) {
      float best = Ss[tid][0];
      int bm = 0;
#pragma unroll
      for (int mm = 1; mm < MM; ++mm) {
        float vv = Ss[tid][mm];
        if (vv > best) { best = vv; bm = mm; }
      }
      codes[(size_t)((b * RR + r) * HH + h) * NN + nc * 64 + tid] = bm;
    }
    __syncthreads();
  }
}

// ---------------------------------------------------------------------------
// Kernel 2: stable counting sort (unchanged — valence scaling is monotone,
// argsort order invariant, inputs 3/5 dead)
// ---------------------------------------------------------------------------
__global__ __launch_bounds__(256) void k_sort(const int* __restrict__ codes,
                                              int* __restrict__ idxo) {
  int g = blockIdx.x;
  const int* cg = codes + (size_t)g * NN;
  int* ig = idxo + (size_t)g * NN;
  __shared__ int hist[256][MM];
  __shared__ int startk[MM];
  int tid = threadIdx.x;
  int myc[16];
#pragma unroll
  for (int qd = 0; qd < 4; ++qd) {
    int4 t4 = ((const int4*)(cg + tid * 16))[qd];
    myc[qd * 4 + 0] = t4.x; myc[qd * 4 + 1] = t4.y;
    myc[qd * 4 + 2] = t4.z; myc[qd * 4 + 3] = t4.w;
  }
  u64 cnt64 = 0ull;
#pragma unroll
  for (int i = 0; i < 16; ++i) cnt64 += 1ull << (myc[i] * 8);
#pragma unroll
  for (int k = 0; k < MM; ++k) hist[tid][k] = (int)((cnt64 >> (k * 8)) & 0xffull);
  __syncthreads();
  if (tid < MM) {
    int run = 0;
    for (int t = 0; t < 256; ++t) { int vv = hist[t][tid]; hist[t][tid] = run; run += vv; }
    startk[tid] = run;
  }
  __syncthreads();
  if (tid == 0) {
    int base = 0;
#pragma unroll
    for (int k = 0; k < MM; ++k) { int vv = startk[k]; startk[k] = base; base += vv; }
  }
  __syncthreads();
#pragma unroll
  for (int i = 0; i < 16; ++i) {
    int k = myc[i];
    int off = hist[tid][k];
    hist[tid][k] = off + 1;
    ig[startk[k] + off] = tid * 16 + i;
  }
}

// ---------------------------------------------------------------------------
// Kernel 3: bucketed attention on MFMA (16x16x32 bf16, split-bf16 for f32 acc).
// Block = (b,h,c), 4 waves; wave w owns output rows [16w,16w+16).
// LDS 40KB: Qhi|Qlo|K/Phi|K/Plo|VT  (P aliases K after QK^T) -> 4 blocks/CU.
// All tiles [64][128B] XOR-swizzled (byte ^= (row&7)<<4).
// k-map inside each MFMA: k = 8*(lane>>4)+b, identical for A and B fragments
// (any consistent map is correct by operand symmetry).
// ---------------------------------------------------------------------------
__global__ __launch_bounds__(256, 4) void k_attn(const float* __restrict__ q,
                                                 const float* __restrict__ kmat,
                                                 const float* __restrict__ vmat,
                                                 const int* __restrict__ idxs,
                                                 float* __restrict__ out,
                                                 float* __restrict__ attn_part,
                                                 float* __restrict__ attn_out,
                                                 int atomic_attn) {
  __shared__ __align__(16) char smbuf[40960];
  char* QHI = smbuf;            // 8KB  Q hi
  char* QLO = smbuf + 8192;     // 8KB  Q lo
  char* KPH = smbuf + 16384;    // 8KB  K hi, then P hi
  char* KPL = smbuf + 24576;    // 8KB  K lo, then P lo
  char* VTB = smbuf + 32768;    // 8KB  V transposed (hi only)

  // XCD-aware swizzle: 2048 blocks, 8 XCDs, chunk=256 -> 4 (b,h) panels/XCD
  int blk = ((int)blockIdx.x & 7) * 256 + ((int)blockIdx.x >> 3);
  int cblk = blk & 63;
  int h = (blk >> 6) & 15;
  int b = blk >> 10;
  int tid = threadIdx.x;
  int lane = tid & 63;
  int w = tid >> 6;
  int g = lane >> 4;
  int cl = lane & 15;

  const float* qbase = q + ((size_t)(b * NN + cblk * 64) * DD + h * DH);
  // ---- stage Q hi/lo (once per block) ----
#pragma unroll
  for (int it = 0; it < 4; ++it) {
    int f = tid + it * 256;
    int row = f >> 4, c4 = f & 15;
    float4 v4 = *(const float4*)(qbase + (size_t)row * DD + c4 * 4);
    const float* vf = (const float*)&v4;
    u64 hp = 0, lp = 0;
#pragma unroll
    for (int j = 0; j < 4; ++j) {
      unsigned short hb = f2bf(vf[j]);
      unsigned short lb = f2bf(vf[j] - bf2f(hb));
      hp |= (u64)hb << (16 * j);
      lp |= (u64)lb << (16 * j);
    }
    *(u64*)(QHI + swz(row, c4 * 8)) = hp;
    *(u64*)(QLO + swz(row, c4 * 8)) = lp;
  }
  __syncthreads();

  // hoist Q fragments (r-invariant): row = 16w+cl, k = 32*ks + 8g + b
  bf16x8 qh[2], ql[2];
#pragma unroll
  for (int ks = 0; ks < 2; ++ks) {
    qh[ks] = *(const bf16x8*)(QHI + swz(16 * w + cl, ks * 64 + g * 16));
    ql[ks] = *(const bf16x8*)(QLO + swz(16 * w + cl, ks * 64 + g * 16));
  }

  f32x4 acc_o[4];
  float attA[4][4];
#pragma unroll
  for (int t = 0; t < 4; ++t) {
    acc_o[t] = (f32x4){0.f, 0.f, 0.f, 0.f};
#pragma unroll
    for (int i = 0; i < 4; ++i) attA[t][i] = 0.f;
  }

  const size_t kvbase = (size_t)b * NN * DD + (size_t)h * DH;
  for (int r = 0; r < RR; ++r) {
    const int* idxr = idxs + (size_t)((b * RR + r) * HH + h) * NN + cblk * 64;
    // ---- gather K rows -> Khi/Klo ----
#pragma unroll
    for (int it = 0; it < 4; ++it) {
      int f = tid + it * 256;
      int e = f >> 4, c4 = f & 15;
      int n = idxr[e];
      float4 v4 = *(const float4*)(kmat + kvbase + (size_t)n * DD + c4 * 4);
      const float* vf = (const float*)&v4;
      u64 hp = 0, lp = 0;
#pragma unroll
      for (int j = 0; j < 4; ++j) {
        unsigned short hb = f2bf(vf[j]);
        unsigned short lb = f2bf(vf[j] - bf2f(hb));
        hp |= (u64)hb << (16 * j);
        lp |= (u64)lb << (16 * j);
      }
      *(u64*)(KPH + swz(e, c4 * 8)) = hp;
      *(u64*)(KPL + swz(e, c4 * 8)) = lp;
    }
    // ---- gather V with 4x4 register transpose -> VT[d][e] (hi only) ----
    {
      int eb = tid & 15, db = tid >> 4;
      float4 vv4[4];
#pragma unroll
      for (int j = 0; j < 4; ++j) {
        int n = idxr[4 * eb + j];
        vv4[j] = *(const float4*)(vmat + kvbase + (size_t)n * DD + db * 4);
      }
#pragma unroll
      for (int jd = 0; jd < 4; ++jd) {
        u64 hp = 0;
#pragma unroll
        for (int j = 0; j < 4; ++j)
          hp |= (u64)f2bf(((const float*)&vv4[j])[jd]) << (16 * j);
        *(u64*)(VTB + swz(db * 4 + jd, eb * 8)) = hp;
      }
    }
    __syncthreads();

    // ---- QK^T: S = Qhi*Khi + Qhi*Klo + Qlo*Khi ----
    f32x4 s4[4];
#pragma unroll
    for (int t = 0; t < 4; ++t) s4[t] = (f32x4){0.f, 0.f, 0.f, 0.f};
#pragma unroll
    for (int t = 0; t < 4; ++t) {
#pragma unroll
      for (int ks = 0; ks < 2; ++ks) {
        bf16x8 kh = *(const bf16x8*)(KPH + swz(16 * t + cl, ks * 64 + g * 16));
        bf16x8 kl = *(const bf16x8*)(KPL + swz(16 * t + cl, ks * 64 + g * 16));
        s4[t] = __builtin_amdgcn_mfma_f32_16x16x32_bf16(qh[ks], kh, s4[t], 0, 0, 0);
        s4[t] = __builtin_amdgcn_mfma_f32_16x16x32_bf16(qh[ks], kl, s4[t], 0, 0, 0);
        s4[t] = __builtin_amdgcn_mfma_f32_16x16x32_bf16(ql[ks], kh, s4[t], 0, 0, 0);
      }
    }
    __syncthreads();  // all waves done reading K before P overwrites region

    // ---- softmax in registers (row s = 16w+4g+i spans 16 lanes of group g) ----
    float p[4][4];
#pragma unroll
    for (int i = 0; i < 4; ++i) {
      float mx = s4[0][i];
#pragma unroll
      for (int t = 1; t < 4; ++t) mx = fmaxf(mx, s4[t][i]);
      mx = fmaxf(mx, __shfl_xor(mx, 1));
      mx = fmaxf(mx, __shfl_xor(mx, 2));
      mx = fmaxf(mx, __shfl_xor(mx, 4));
      mx = fmaxf(mx, __shfl_xor(mx, 8));
      float sm = 0.f;
#pragma unroll
      for (int t = 0; t < 4; ++t) {
        p[t][i] = __expf((s4[t][i] - mx) * 0.125f);
        sm += p[t][i];
      }
      sm += __shfl_xor(sm, 1);
      sm += __shfl_xor(sm, 2);
      sm += __shfl_xor(sm, 4);
      sm += __shfl_xor(sm, 8);
      float inv = 1.f / sm;
#pragma unroll
      for (int t = 0; t < 4; ++t) {
        p[t][i] *= inv;
        attA[t][i] += p[t][i];
      }
    }
    // ---- write P hi/lo to LDS (aliases K region), rows own-wave only ----
#pragma unroll
    for (int i = 0; i < 4; ++i) {
      int srow = 16 * w + 4 * g + i;
#pragma unroll
      for (int t = 0; t < 4; ++t) {
        unsigned short ph = f2bf(p[t][i]);
        unsigned short pl = f2bf(p[t][i] - bf2f(ph));
        int cb = 2 * (16 * t + cl);
        *(unsigned short*)(KPH + swz(srow, cb)) = ph;
        *(unsigned short*)(KPL + swz(srow, cb)) = pl;
      }
    }
    // ---- PV: O += (Phi+Plo) * VT ----
    bf16x8 pf[2], pl2[2];
#pragma unroll
    for (int ks = 0; ks < 2; ++ks) {
      pf[ks]  = *(const bf16x8*)(KPH + swz(16 * w + cl, ks * 64 + g * 16));
      pl2[ks] = *(const bf16x8*)(KPL + swz(16 * w + cl, ks * 64 + g * 16));
    }
#pragma unroll
    for (int t = 0; t < 4; ++t) {
#pragma unroll
      for (int ks = 0; ks < 2; ++ks) {
        bf16x8 vt = *(const bf16x8*)(VTB + swz(16 * t + cl, ks * 64 + g * 16));
        acc_o[t] = __builtin_amdgcn_mfma_f32_16x16x32_bf16(pf[ks], vt, acc_o[t], 0, 0, 0);
        acc_o[t] = __builtin_amdgcn_mfma_f32_16x16x32_bf16(pl2[ks], vt, acc_o[t], 0, 0, 0);
      }
    }
    __syncthreads();  // before next r overwrites K/P and VT
  }

  // ---- epilogue: out = mean_r O ; attn accumulation ----
#pragma unroll
  for (int i = 0; i < 4; ++i) {
    int srow = 16 * w + 4 * g + i;
    size_t obase = (size_t)(b * NN + cblk * 64 + srow) * DD + h * DH;
#pragma unroll
    for (int t = 0; t < 4; ++t)
      out[obase + 16 * t + cl] = acc_o[t][i] * 0.25f;
  }
  if (atomic_attn) {
    const float sc = 1.f / (RR * HH);
#pragma unroll
    for (int i = 0; i < 4; ++i) {
      int srow = 16 * w + 4 * g + i;
#pragma unroll
      for (int t = 0; t < 4; ++t)
        atomicAdd(attn_out + (((size_t)b * CC + cblk) * 64 + srow) * 64 + 16 * t + cl,
                  attA[t][i] * sc);
    }
  } else {
#pragma unroll
    for (int i = 0; i < 4; ++i) {
      int srow = 16 * w + 4 * g + i;
#pragma unroll
      for (int t = 0; t < 4; ++t)
        attn_part[(((size_t)(b * HH + h) * CC + cblk) * 64 + srow) * 64 + 16 * t + cl] =
            attA[t][i];
    }
  }
}

// ---------------------------------------------------------------------------
// Kernel 4: attn_out = (1/(R*H)) * sum_h attn_part (unchanged)
// ---------------------------------------------------------------------------
__global__ __launch_bounds__(256) void k_attn_reduce(const float* __restrict__ part,
                                                     float* __restrict__ attn_out) {
  size_t o = (size_t)blockIdx.x * 256 + threadIdx.x;
  int se = (int)(o & 4095);
  size_t bc = o >> 12;
  int c = (int)(bc & (CC - 1));
  int b = (int)(bc >> 6);
  float s = 0.f;
  const float* p = part + ((size_t)b * HH * CC + c) * 4096 + se;
#pragma unroll
  for (int h = 0; h < HH; ++h) s += p[(size_t)h * CC * 4096];
  attn_out[o] = s * (1.f / (RR * HH));
}

extern "C" void kernel_launch(void* const* d_in, const int* in_sizes, int n_in,
                              void* d_out, int out_size, void* d_ws, size_t ws_size,
                              hipStream_t stream) {
  const float* q = (const float*)d_in[0];
  const float* k = (const float*)d_in[1];
  const float* v = (const float*)d_in[2];
  const float* proj = (const float*)d_in[4];
  float* out = (float*)d_out;
  float* attn_out = out + (size_t)BB * NN * DD;

  int* codes = (int*)d_ws;
  int* idxs = codes + (size_t)BB * RR * HH * NN;
  float* attn_part = (float*)(idxs + (size_t)BB * RR * HH * NN);
  size_t need = (size_t)BB * RR * HH * NN * 8 + (size_t)BB * HH * CC * 4096 * 4;
  int atomic_attn = (ws_size < need) ? 1 : 0;
  if (atomic_attn)
    hipMemsetAsync(attn_out, 0, (size_t)BB * CC * 4096 * sizeof(float), stream);

  k_hash<<<BB * HH * CC, 256, 0, stream>>>(q, proj, codes);
  k_sort<<<BB * RR * HH, 256, 0, stream>>>(codes, idxs);
  k_attn<<<BB * HH * CC, 256, 0, stream>>>(q, k, v, idxs, out, attn_part, attn_out, atomic_attn);
  if (!atomic_attn)
    k_attn_reduce<<<BB * CC * 4096 / 256, 256, 0, stream>>>(attn_part, attn_out);
}